// Round 9
// baseline (352.323 us; speedup 1.0000x reference)
//
#include <hip/hip_runtime.h>
#include <hip/hip_bf16.h>

// KNN_itc: out[b][n] = sum over support descriptors m (441) of top-3 (over 441
// query descriptors) cosine similarities, C=640, bf16 MFMA.
//
// R9:
//  - prep_kernel : unchanged from R8 (contiguous 113KB f32 reads, bf16 pack to
//    fragment-linear chunks, deferred normalization partials).
//  - gemm_top3   : BK=32 DOUBLE-BUFFERED glds pipeline. Two 32KB LDS buffers;
//    glds(slab s+1 -> other buf) issued BEFORE computing slab s, so the
//    barrier's vmcnt(0) drain overlaps ~1100 cyc of MFMA (R5/R8's 2-barrier
//    structure serialized staging after compute: 4500 cyc/slab vs 2340
//    balanced). One barrier/slab, buffer parity compile-time via 2x unroll.
//    28 MFMA/wave/slab, fragment-linear ds_read (conflict-free), in-register
//    top-3 + shuffle merge + one atomicAdd per block.

#define B_IMGS 75
#define N_CLS  5
#define N_IMGS 80            // 75 query + 5 support
#define C_DIM  640
#define HW     441
#define HWP    448
#define NKT    20            // 640 / 32 k-chunks
#define NRB    28            // 448 / 16 row-blocks per image
#define CHUNK  512           // 16 rows x 32 k elems = 1 KiB

typedef __attribute__((ext_vector_type(8))) short  short8;   // 8 x bf16
typedef __attribute__((ext_vector_type(4))) float  float4v;  // MFMA acc

__device__ __forceinline__ void ins3(float& t0, float& t1, float& t2, float v) {
    float m  = fminf(t0, v);
    t0 = fmaxf(t0, v);
    float m2 = fminf(t1, m);
    t1 = fmaxf(t1, m);
    t2 = fmaxf(t2, m2);
}

__device__ __forceinline__ void glds16(const __hip_bfloat16* g, __hip_bfloat16* l) {
    __builtin_amdgcn_global_load_lds(
        (const __attribute__((address_space(1))) unsigned int*)g,
        (__attribute__((address_space(3))) unsigned int*)l, 16, 0, 0);
}

// ---- prepass: contiguous read + transpose + bf16 pack + sumsq partials ----
// block = (img 0..79, cs 0..9: 64-channel slab); 800 blocks x 256 threads
__global__ __launch_bounds__(256)
void prep_kernel(const float* __restrict__ q, const float* __restrict__ S,
                 __hip_bfloat16* __restrict__ pk, float* __restrict__ normPart) {
    __shared__ __hip_bfloat16 tile[64][449];   // [k_local][hw]; 57.4 KB

    int bid = blockIdx.x;
    int img = bid / 10;                 // 0..79 (0..74 = q, 75..79 = S)
    int cs  = bid % 10;                 // 64-channel slab
    const float* src = (img < B_IMGS)
        ? q + (size_t)img * C_DIM * HW
        : S + (size_t)(img - B_IMGS) * C_DIM * HW;
    __hip_bfloat16* dst = pk + (size_t)img * NRB * NKT * CHUNK;
    const float* base = src + (size_t)cs * 64 * HW;   // contiguous 64x441 f32

    int t = threadIdx.x;
    bool t2ok = (t < HW - 256);         // second segment valid
    float ss0 = 0.f, ss1 = 0.f;
#pragma unroll 4
    for (int cl = 0; cl < 64; ++cl) {
        float v0 = base[cl * HW + t];                       // coalesced, dense
        float v1 = t2ok ? base[cl * HW + 256 + t] : 0.f;
        ss0 += v0 * v0;
        ss1 += v1 * v1;
        tile[cl][t] = __float2bfloat16(v0);
        if (t < HWP - 256) tile[cl][256 + t] = __float2bfloat16(v1);  // pads -> 0
    }
    normPart[((size_t)cs * N_IMGS + img) * HWP + t] = ss0;
    if (t < HWP - 256)
        normPart[((size_t)cs * N_IMGS + img) * HWP + 256 + t] = ss1;
    __syncthreads();

    // pack: fragment-linear chunks; per (rb,kk) a 1KiB coalesced wave store
    int l     = t & 63;
    int wg    = t >> 6;
    int row16 = l & 15;
    int quad  = l >> 4;
#pragma unroll
    for (int i = 0; i < 7; ++i) {
        int rb = i * 4 + wg;
#pragma unroll
        for (int kk = 0; kk < 2; ++kk) {
            short8 v;
#pragma unroll
            for (int j = 0; j < 8; ++j) {
                __hip_bfloat16 h = tile[kk * 32 + quad * 8 + j][rb * 16 + row16];
                v[j] = *(short*)&h;
            }
            *(short8*)(dst + ((size_t)rb * NKT + cs * 2 + kk) * CHUNK + l * 8) = v;
        }
    }
}

// ------------- gemm + fused top-3: double-buffered glds pipeline -------------
__global__ __launch_bounds__(256, 2)
void gemm_top3_kernel(const __hip_bfloat16* __restrict__ pk,
                      const float* __restrict__ normPart,
                      float* __restrict__ out) {
    __shared__ __hip_bfloat16 sbuf0[32 * CHUNK];  // 32 KiB: 28 A + 4 B chunks
    __shared__ __hip_bfloat16 sbuf1[32 * CHUNK];  // 32 KiB
    __shared__ float mrg[4][64][3];
    __shared__ float sInvQ[HWP];
    __shared__ float sInvS[64];

    // XCD-grouping swizzle: all 35 (n,mt) blocks of image b on one XCD
    int id  = blockIdx.x;
    int xcd = id & 7;
    int j8  = id >> 3;
    int b   = (j8 / 35) * 8 + xcd;
    if (b >= B_IMGS) return;
    int inner = j8 % 35;
    int n  = inner / 7;
    int mt = inner % 7;

    int tid  = threadIdx.x;
    int w    = tid >> 6;
    int l    = tid & 63;
    int c16  = l & 15;
    int quad = l >> 4;

    const __hip_bfloat16* qA = pk + (size_t)b * NRB * NKT * CHUNK;
    const __hip_bfloat16* qB = pk + ((size_t)(B_IMGS + n) * NRB + mt * 4) * NKT * CHUNK;

#define STAGE(BUF, KT) do {                                                   \
    _Pragma("unroll")                                                         \
    for (int i_ = 0; i_ < 8; ++i_) {                                          \
        int cid_ = w * 8 + i_;                                                \
        const __hip_bfloat16* g_ = (cid_ < 28)                                \
            ? qA + ((size_t)cid_ * NKT + (KT)) * CHUNK                        \
            : qB + ((size_t)(cid_ - 28) * NKT + (KT)) * CHUNK;                \
        glds16(g_ + l * 8, (BUF) + cid_ * CHUNK + l * 8);                     \
    } } while (0)

#define COMPUTE(BUF) do {                                                     \
    short8 a_[7], b_[4];                                                      \
    _Pragma("unroll")                                                         \
    for (int r_ = 0; r_ < 7; ++r_)                                            \
        a_[r_] = *(const short8*)((BUF) + (r_ * 4 + w) * CHUNK + l * 8);      \
    _Pragma("unroll")                                                         \
    for (int j_ = 0; j_ < 4; ++j_)                                            \
        b_[j_] = *(const short8*)((BUF) + (28 + j_) * CHUNK + l * 8);         \
    _Pragma("unroll")                                                         \
    for (int r_ = 0; r_ < 7; ++r_)                                            \
        _Pragma("unroll")                                                     \
        for (int j_ = 0; j_ < 4; ++j_)                                        \
            acc[r_][j_] = __builtin_amdgcn_mfma_f32_16x16x32_bf16(            \
                a_[r_], b_[j_], acc[r_][j_], 0, 0, 0);                        \
    } while (0)

    float4v acc[7][4];
#pragma unroll
    for (int r = 0; r < 7; ++r)
#pragma unroll
        for (int j = 0; j < 4; ++j)
            acc[r][j] = (float4v){0.f, 0.f, 0.f, 0.f};

    // --- stage slab 0 (async; overlaps the norm preamble below) ---
    STAGE(sbuf0, 0);

    // --- inv norms from the 10 per-slab partials (L2/L3-hot) ---
    {
        float s0 = 0.f, s1 = 0.f, s2 = 0.f;
#pragma unroll
        for (int cs = 0; cs < 10; ++cs) {
            const float* npq = normPart + ((size_t)cs * N_IMGS + b) * HWP;
            s0 += npq[tid];
            if (tid < HWP - 256) s1 += npq[256 + tid];
            if (tid < 64)
                s2 += normPart[((size_t)cs * N_IMGS + B_IMGS + n) * HWP + mt * 64 + tid];
        }
        sInvQ[tid] = (tid < HW) ? rsqrtf(s0) : 0.f;
        if (tid < HWP - 256)
            sInvQ[256 + tid] = ((256 + tid) < HW) ? rsqrtf(s1) : 0.f;
        if (tid < 64)
            sInvS[tid] = ((mt * 64 + tid) < HW) ? rsqrtf(s2) : 0.f;
    }

    __syncthreads();                     // slab 0 staged + norms visible

    for (int ss = 0; ss < 10; ++ss) {
        // slab 2ss (in sbuf0); prefetch 2ss+1 -> sbuf1 first
        STAGE(sbuf1, 2 * ss + 1);
        COMPUTE(sbuf0);
        __syncthreads();                 // sbuf1 staged; sbuf0 reads done
        // slab 2ss+1 (in sbuf1); prefetch 2ss+2 -> sbuf0
        if (ss < 9) STAGE(sbuf0, 2 * ss + 2);
        COMPUTE(sbuf1);
        __syncthreads();                 // sbuf0 staged; sbuf1 reads done
    }
#undef STAGE
#undef COMPUTE

    // ---- in-register top-3 over this wave's 112 rows (v = acc * invq[row]) ----
    float T0[4], T1[4], T2[4];
#pragma unroll
    for (int j = 0; j < 4; ++j) { T0[j] = -1e30f; T1[j] = -1e30f; T2[j] = -1e30f; }
#pragma unroll
    for (int r = 0; r < 7; ++r)
#pragma unroll
        for (int g = 0; g < 4; ++g) {
            int row = r * 64 + w * 16 + quad * 4 + g;   // C layout: row=quad*4+reg
            float iv = sInvQ[row];
            bool valid = row < HW;
#pragma unroll
            for (int j = 0; j < 4; ++j) {
                float v = valid ? acc[r][j][g] * iv : -1e30f;
                ins3(T0[j], T1[j], T2[j], v);
            }
        }

    // quad-butterfly merge (rows spread over lane bits 4,5)
#pragma unroll
    for (int j = 0; j < 4; ++j) {
#pragma unroll
        for (int d = 16; d <= 32; d <<= 1) {
            float o0 = __shfl_xor(T0[j], d, 64);
            float o1 = __shfl_xor(T1[j], d, 64);
            float o2 = __shfl_xor(T2[j], d, 64);
            ins3(T0[j], T1[j], T2[j], o0);
            ins3(T0[j], T1[j], T2[j], o1);
            ins3(T0[j], T1[j], T2[j], o2);
        }
    }

    // cross-wave merge via LDS
    if (quad == 0) {
#pragma unroll
        for (int j = 0; j < 4; ++j) {
            mrg[w][j * 16 + c16][0] = T0[j];
            mrg[w][j * 16 + c16][1] = T1[j];
            mrg[w][j * 16 + c16][2] = T2[j];
        }
    }
    __syncthreads();
    if (tid < 64) {
        int col = tid;
        float t0 = mrg[0][col][0], t1 = mrg[0][col][1], t2 = mrg[0][col][2];
#pragma unroll
        for (int ww = 1; ww < 4; ++ww) {
            ins3(t0, t1, t2, mrg[ww][col][0]);
            ins3(t0, t1, t2, mrg[ww][col][1]);
            ins3(t0, t1, t2, mrg[ww][col][2]);
        }
        float isv = sInvS[col];
        float s = (mt * 64 + col < HW) ? (t0 + t1 + t2) * isv : 0.f;
#pragma unroll
        for (int d = 32; d >= 1; d >>= 1) s += __shfl_xor(s, d, 64);
        if (tid == 0) atomicAdd(&out[b * N_CLS + n], s);
    }
}

extern "C" void kernel_launch(void* const* d_in, const int* in_sizes, int n_in,
                              void* d_out, int out_size, void* d_ws, size_t ws_size,
                              hipStream_t stream) {
    const float* q = (const float*)d_in[0];
    const float* S = (const float*)d_in[1];
    float* out = (float*)d_out;

    char* ws = (char*)d_ws;
    size_t off = 0;
    __hip_bfloat16* pk = (__hip_bfloat16*)(ws + off);     // 80 imgs packed
    off += (size_t)N_IMGS * NRB * NKT * CHUNK * 2;  off = (off + 255) & ~(size_t)255;
    float* normPart = (float*)(ws + off);                 // [10][80][HWP]

    hipMemsetAsync(d_out, 0, (size_t)out_size * sizeof(float), stream);

    prep_kernel<<<dim3(N_IMGS * 10), dim3(256), 0, stream>>>(q, S, pk, normPart);
    // 8 XCD groups x 350 slots; dead blocks (b>=75) exit immediately
    gemm_top3_kernel<<<dim3(8 * 350), dim3(256), 0, stream>>>(pk, normPart, out);
}

// Round 10
// 311.922 us; speedup vs baseline: 1.1295x; 1.1295x over previous
//
#include <hip/hip_runtime.h>
#include <hip/hip_bf16.h>

// KNN_itc: out[b][n] = sum over support descriptors m (441) of top-3 (over 441
// query descriptors) cosine similarities, C=640, fp8 MFMA (non-scaled = bf16
// rate, half the staging bytes — staging BW was the R5..R9 ceiling).
//
// R10:
//  - prep_kernel : R8 structure (contiguous 113KB f32 reads, bf16 LDS tile,
//    deferred-normalization sumsq partials) but packs fp8 e4m3, kt-major:
//    chunk[(kt*28+rb)] of 512B; lane l's 8-byte MFMA fragment
//    (row=l&15, k=(l>>4)*8+j) at byte l*8. Slab (one kt) = contiguous 14KiB.
//  - gemm_top3   : BK=64 double-buffered glds pipeline, 1 barrier/slab,
//    10 slabs. Slab = 32KB (28 A-KiB + 4 B-KiB as 32 glds16 units of 1024B).
//    56 MFMA/wave/slab (mfma_f32_16x16x32_fp8_fp8, i64 frags, ds_read_b64).
//    Epilogue: v = acc * invq[row], top-3 in regs, shuffle merge, * invs[col],
//    one atomicAdd per block. Norms from f32 partials (exact).

#define B_IMGS 75
#define N_CLS  5
#define N_IMGS 80            // 75 query + 5 support
#define C_DIM  640
#define HW     441
#define HWP    448
#define NKT    20            // 640 / 32 k-chunks
#define NRB    28            // 448 / 16 row-blocks per image
#define CHB    512           // chunk bytes: 16 rows x 32 k x 1B
#define KTB    (NRB * CHB)   // 14336 B per kt slab per image

typedef __attribute__((ext_vector_type(4))) float float4v;  // MFMA acc

__device__ __forceinline__ void ins3(float& t0, float& t1, float& t2, float v) {
    float m  = fminf(t0, v);
    t0 = fmaxf(t0, v);
    float m2 = fminf(t1, m);
    t1 = fmaxf(t1, m);
    t2 = fmaxf(t2, m2);
}

__device__ __forceinline__ void glds16(const unsigned char* g, unsigned char* l) {
    __builtin_amdgcn_global_load_lds(
        (const __attribute__((address_space(1))) unsigned int*)g,
        (__attribute__((address_space(3))) unsigned int*)l, 16, 0, 0);
}

// ---- prepass: contiguous read + bf16 tile + fp8 pack + sumsq partials ----
// block = (img 0..79, cs 0..9: 64-channel slab); 800 blocks x 256 threads
__global__ __launch_bounds__(256)
void prep_kernel(const float* __restrict__ q, const float* __restrict__ S,
                 unsigned char* __restrict__ pk, float* __restrict__ normPart) {
    __shared__ __hip_bfloat16 tile[64][449];   // [k_local][hw]; 57.4 KB

    int bid = blockIdx.x;
    int img = bid / 10;                 // 0..79 (0..74 = q, 75..79 = S)
    int cs  = bid % 10;                 // 64-channel slab
    const float* src = (img < B_IMGS)
        ? q + (size_t)img * C_DIM * HW
        : S + (size_t)(img - B_IMGS) * C_DIM * HW;
    unsigned char* dst = pk + (size_t)img * NKT * KTB;
    const float* base = src + (size_t)cs * 64 * HW;   // contiguous 64x441 f32

    int t = threadIdx.x;
    bool t2ok = (t < HW - 256);         // second segment valid
    float ss0 = 0.f, ss1 = 0.f;
#pragma unroll 4
    for (int cl = 0; cl < 64; ++cl) {
        float v0 = base[cl * HW + t];                       // coalesced, dense
        float v1 = t2ok ? base[cl * HW + 256 + t] : 0.f;
        ss0 += v0 * v0;
        ss1 += v1 * v1;
        tile[cl][t] = __float2bfloat16(v0);
        if (t < HWP - 256) tile[cl][256 + t] = __float2bfloat16(v1);  // pads -> 0
    }
    normPart[((size_t)cs * N_IMGS + img) * HWP + t] = ss0;
    if (t < HWP - 256)
        normPart[((size_t)cs * N_IMGS + img) * HWP + 256 + t] = ss1;
    __syncthreads();

    // pack: fp8 fragment-linear chunks, kt-major; 512B coalesced wave stores
    int l     = t & 63;
    int wg    = t >> 6;
    int row16 = l & 15;
    int quad  = l >> 4;
#pragma unroll
    for (int i = 0; i < 7; ++i) {
        int rb = i * 4 + wg;
#pragma unroll
        for (int kk = 0; kk < 2; ++kk) {
            float f[8];
#pragma unroll
            for (int j = 0; j < 8; ++j)
                f[j] = __bfloat162float(tile[kk * 32 + quad * 8 + j][rb * 16 + row16]);
            int lo = 0, hi = 0;
            lo = __builtin_amdgcn_cvt_pk_fp8_f32(f[0], f[1], lo, false);
            lo = __builtin_amdgcn_cvt_pk_fp8_f32(f[2], f[3], lo, true);
            hi = __builtin_amdgcn_cvt_pk_fp8_f32(f[4], f[5], hi, false);
            hi = __builtin_amdgcn_cvt_pk_fp8_f32(f[6], f[7], hi, true);
            int2 v = make_int2(lo, hi);
            *(int2*)(dst + ((size_t)(cs * 2 + kk) * NRB + rb) * CHB + l * 8) = v;
        }
    }
}

// ------------- gemm + fused top-3: fp8, BK=64 double-buffered glds -------------
__global__ __launch_bounds__(256, 2)
void gemm_top3_kernel(const unsigned char* __restrict__ pk,
                      const float* __restrict__ normPart,
                      float* __restrict__ out) {
    __shared__ unsigned char sbuf[2][32768];   // 64 KiB total
    __shared__ float mrg[4][64][3];
    __shared__ float sInvQ[HWP];
    __shared__ float sInvS[64];

    // XCD-grouping swizzle: all 35 (n,mt) blocks of image b on one XCD
    int id  = blockIdx.x;
    int xcd = id & 7;
    int j8  = id >> 3;
    int b   = (j8 / 35) * 8 + xcd;
    if (b >= B_IMGS) return;
    int inner = j8 % 35;
    int n  = inner / 7;
    int mt = inner % 7;

    int tid  = threadIdx.x;
    int w    = tid >> 6;
    int l    = tid & 63;
    int c16  = l & 15;
    int quad = l >> 4;

    const unsigned char* Abase = pk + (size_t)b * NKT * KTB;
    const unsigned char* Bbase = pk + (size_t)(B_IMGS + n) * NKT * KTB;

    // stage slab s (kt pair 2s,2s+1): A = 28 KiB contiguous, B = 2x2 KiB
#define STAGE(BUF, SS) do {                                                   \
    _Pragma("unroll")                                                         \
    for (int i_ = 0; i_ < 8; ++i_) {                                          \
        int u_ = w * 8 + i_;                                                  \
        const unsigned char* g_;                                              \
        if (u_ < 28) {                                                        \
            g_ = Abase + (size_t)(2 * (SS)) * KTB + u_ * 1024;                \
        } else {                                                              \
            int v_ = u_ - 28;                                                 \
            g_ = Bbase + (size_t)(2 * (SS) + (v_ >> 1)) * KTB                 \
               + mt * 2048 + (v_ & 1) * 1024;                                 \
        }                                                                     \
        glds16(g_ + l * 16, (BUF) + u_ * 1024 + l * 16);                      \
    } } while (0)

#define COMPUTE(BUF) do {                                                     \
    _Pragma("unroll")                                                         \
    for (int kk_ = 0; kk_ < 2; ++kk_) {                                       \
        long a_[7], bq_[4];                                                   \
        _Pragma("unroll")                                                     \
        for (int r_ = 0; r_ < 7; ++r_)                                        \
            a_[r_] = *(const long*)((BUF) + kk_ * KTB                         \
                       + (r_ * 4 + w) * CHB + l * 8);                         \
        _Pragma("unroll")                                                     \
        for (int j_ = 0; j_ < 4; ++j_)                                        \
            bq_[j_] = *(const long*)((BUF) + 28672 + kk_ * 2048               \
                       + j_ * CHB + l * 8);                                   \
        _Pragma("unroll")                                                     \
        for (int r_ = 0; r_ < 7; ++r_)                                        \
            _Pragma("unroll")                                                 \
            for (int j_ = 0; j_ < 4; ++j_)                                    \
                acc[r_][j_] = __builtin_amdgcn_mfma_f32_16x16x32_fp8_fp8(     \
                    a_[r_], bq_[j_], acc[r_][j_], 0, 0, 0);                   \
    } } while (0)

    float4v acc[7][4];
#pragma unroll
    for (int r = 0; r < 7; ++r)
#pragma unroll
        for (int j = 0; j < 4; ++j)
            acc[r][j] = (float4v){0.f, 0.f, 0.f, 0.f};

    STAGE(sbuf[0], 0);                   // async; overlaps norm preamble

    // --- inv norms from the 10 per-slab partials (L2/L3-hot) ---
    {
        float s0 = 0.f, s1 = 0.f, s2 = 0.f;
#pragma unroll
        for (int cs = 0; cs < 10; ++cs) {
            const float* npq = normPart + ((size_t)cs * N_IMGS + b) * HWP;
            s0 += npq[tid];
            if (tid < HWP - 256) s1 += npq[256 + tid];
            if (tid < 64)
                s2 += normPart[((size_t)cs * N_IMGS + B_IMGS + n) * HWP + mt * 64 + tid];
        }
        sInvQ[tid] = (tid < HW) ? rsqrtf(s0) : 0.f;
        if (tid < HWP - 256)
            sInvQ[256 + tid] = ((256 + tid) < HW) ? rsqrtf(s1) : 0.f;
        if (tid < 64)
            sInvS[tid] = ((mt * 64 + tid) < HW) ? rsqrtf(s2) : 0.f;
    }

    __syncthreads();                     // slab 0 staged + norms visible

#pragma unroll
    for (int ss = 0; ss < 5; ++ss) {
        STAGE(sbuf[1], 2 * ss + 1);
        COMPUTE(sbuf[0]);
        __syncthreads();                 // sbuf1 staged; sbuf0 reads done
        if (ss < 4) STAGE(sbuf[0], 2 * ss + 2);
        COMPUTE(sbuf[1]);
        __syncthreads();                 // sbuf0 staged; sbuf1 reads done
    }
#undef STAGE
#undef COMPUTE

    // ---- in-register top-3 over this wave's 112 rows (v = acc * invq[row]) ----
    float T0[4], T1[4], T2[4];
#pragma unroll
    for (int j = 0; j < 4; ++j) { T0[j] = -1e30f; T1[j] = -1e30f; T2[j] = -1e30f; }
#pragma unroll
    for (int r = 0; r < 7; ++r)
#pragma unroll
        for (int g = 0; g < 4; ++g) {
            int row = r * 64 + w * 16 + quad * 4 + g;   // C layout: row=quad*4+reg
            float iv = sInvQ[row];
            bool valid = row < HW;
#pragma unroll
            for (int j = 0; j < 4; ++j) {
                float v = valid ? acc[r][j][g] * iv : -1e30f;
                ins3(T0[j], T1[j], T2[j], v);
            }
        }

    // quad-butterfly merge (rows spread over lane bits 4,5)
#pragma unroll
    for (int j = 0; j < 4; ++j) {
#pragma unroll
        for (int d = 16; d <= 32; d <<= 1) {
            float o0 = __shfl_xor(T0[j], d, 64);
            float o1 = __shfl_xor(T1[j], d, 64);
            float o2 = __shfl_xor(T2[j], d, 64);
            ins3(T0[j], T1[j], T2[j], o0);
            ins3(T0[j], T1[j], T2[j], o1);
            ins3(T0[j], T1[j], T2[j], o2);
        }
    }

    // cross-wave merge via LDS
    if (quad == 0) {
#pragma unroll
        for (int j = 0; j < 4; ++j) {
            mrg[w][j * 16 + c16][0] = T0[j];
            mrg[w][j * 16 + c16][1] = T1[j];
            mrg[w][j * 16 + c16][2] = T2[j];
        }
    }
    __syncthreads();
    if (tid < 64) {
        int col = tid;
        float t0 = mrg[0][col][0], t1 = mrg[0][col][1], t2 = mrg[0][col][2];
#pragma unroll
        for (int ww = 1; ww < 4; ++ww) {
            ins3(t0, t1, t2, mrg[ww][col][0]);
            ins3(t0, t1, t2, mrg[ww][col][1]);
            ins3(t0, t1, t2, mrg[ww][col][2]);
        }
        float isv = sInvS[col];
        float s = (mt * 64 + col < HW) ? (t0 + t1 + t2) * isv : 0.f;
#pragma unroll
        for (int d = 32; d >= 1; d >>= 1) s += __shfl_xor(s, d, 64);
        if (tid == 0) atomicAdd(&out[b * N_CLS + n], s);
    }
}

extern "C" void kernel_launch(void* const* d_in, const int* in_sizes, int n_in,
                              void* d_out, int out_size, void* d_ws, size_t ws_size,
                              hipStream_t stream) {
    const float* q = (const float*)d_in[0];
    const float* S = (const float*)d_in[1];
    float* out = (float*)d_out;

    char* ws = (char*)d_ws;
    size_t off = 0;
    unsigned char* pk = (unsigned char*)(ws + off);       // 80 imgs, fp8 packed
    off += (size_t)N_IMGS * NKT * KTB;              off = (off + 255) & ~(size_t)255;
    float* normPart = (float*)(ws + off);                 // [10][80][HWP]

    hipMemsetAsync(d_out, 0, (size_t)out_size * sizeof(float), stream);

    prep_kernel<<<dim3(N_IMGS * 10), dim3(256), 0, stream>>>(q, S, pk, normPart);
    // 8 XCD groups x 350 slots; dead blocks (b>=75) exit immediately
    gemm_top3_kernel<<<dim3(8 * 350), dim3(256), 0, stream>>>(pk, normPart, out);
}